// Round 3
// baseline (68664.899 us; speedup 1.0000x reference)
//
#include <hip/hip_runtime.h>
#include <math.h>

#define BS   16384
#define HID  1024
#define G4   4096
#define EMB  512
#define WVD  300
#define IND  812
#define VOC  258
#define NST  14

__device__ __forceinline__ float sigf(float x){ return 1.0f/(1.0f+expf(-x)); }
__device__ __forceinline__ double dsig(double x){ return 1.0/(1.0+exp(-x)); }
__device__ __forceinline__ double dtanh_(double x){
  double ax = fabs(x);
  double e = exp(-2.0*ax);
  double t = (1.0-e)/(1.0+e);
  return x < 0.0 ? -t : t;
}

// ======================= f64 path =======================

// E = emb @ W_ih[:, :512].T  -> f64 [VOC][G4]
#define ETT 16
__global__ __launch_bounds__(256) void ekernel_f64(const float* __restrict__ emb,
                                                   const float* __restrict__ Wih,
                                                   double* __restrict__ E){
  __shared__ float elds[ETT][EMB];
  const int tid = threadIdx.x;
  const int n  = blockIdx.x*256 + tid;      // 0..4095
  const int t0 = blockIdx.y*ETT;
  #pragma unroll
  for (int i = 0; i < 8; ++i){
    int fi = tid + 256*i;
    int tt = fi >> 7;
    int kk = (fi & 127) << 2;
    float4 v = make_float4(0.f,0.f,0.f,0.f);
    if (t0+tt < VOC) v = *(const float4*)(emb + (size_t)(t0+tt)*EMB + kk);
    *(float4*)&elds[tt][kk] = v;
  }
  __syncthreads();
  double acc[ETT];
  #pragma unroll
  for (int tt=0;tt<ETT;++tt) acc[tt]=0.0;
  const float* wr = Wih + (size_t)n*IND;
  for (int k=0;k<EMB;k+=4){
    float4 w = *(const float4*)(wr + k);
    double w0=w.x, w1=w.y, w2=w.z, w3=w.w;
    #pragma unroll
    for (int tt=0;tt<ETT;++tt){
      float4 e = *(const float4*)&elds[tt][k];
      acc[tt] += (double)e.x*w0 + (double)e.y*w1 + (double)e.z*w2 + (double)e.w*w3;
    }
  }
  #pragma unroll
  for (int tt=0;tt<ETT;++tt){
    int t = t0+tt;
    if (t < VOC) E[(size_t)t*G4 + n] = acc[tt];
  }
}

// fused gates GEMM (f64) + LSTM cell. rows are chunk-relative.
// block: 128 rows x 32 units (=128 gate cols). 256 thr, 8x8 f64 acc.
// B col c -> gate g=c>>5, unit ul=c&31. thread's cols: c_j = tx + 16*j.
__global__ __launch_bounds__(256) void gates_f64(
    const double* __restrict__ hin, double* __restrict__ hout,
    double* __restrict__ cst, const int* __restrict__ idx,
    const double* __restrict__ E,
    const float* __restrict__ Whh, const float* __restrict__ Wih,
    const float* __restrict__ wv,
    const float* __restrict__ bih, const float* __restrict__ bhh,
    int nht)
{
  __shared__ double Al[32][132];
  __shared__ double Bl[32][132];
  const int tid = threadIdx.x;
  const int r0 = blockIdx.x * 128;
  const int u0 = blockIdx.y * 32;
  const int tx = tid & 15, ty = tid >> 4;
  double acc[8][8];
  #pragma unroll
  for (int i=0;i<8;++i)
    #pragma unroll
    for (int j=0;j<8;++j) acc[i][j]=0.0;

  const int nwt = 10;                       // ceil(300/32) word_vec tiles
  const int ra = tid >> 1;                  // 0..127 : A row / B col
  const int kb = (tid & 1) * 16;            // 0 / 16
  const int wrow = (ra >> 5)*HID + u0 + (ra & 31);  // W row for B col ra

  for (int t = 0; t < nht + nwt; ++t){
    if (t < nht){
      int k0 = t*32;
      const double* s0 = hin + (size_t)(r0+ra)*HID + k0 + kb;
      #pragma unroll
      for (int jj=0;jj<8;++jj){
        double2 v = *(const double2*)(s0 + 2*jj);
        Al[kb+2*jj  ][ra] = v.x;
        Al[kb+2*jj+1][ra] = v.y;
      }
      const float* s1 = Whh + (size_t)wrow*HID + k0 + kb;
      #pragma unroll
      for (int jj=0;jj<4;++jj){
        float4 w = *(const float4*)(s1 + 4*jj);
        Bl[kb+4*jj  ][ra] = (double)w.x;
        Bl[kb+4*jj+1][ra] = (double)w.y;
        Bl[kb+4*jj+2][ra] = (double)w.z;
        Bl[kb+4*jj+3][ra] = (double)w.w;
      }
    } else {
      int k0 = (t - nht)*32;
      #pragma unroll
      for (int jj=0;jj<16;++jj){
        int k = k0 + kb + jj;
        Al[kb+jj][ra] = (k < WVD) ? (double)wv[(size_t)(r0+ra)*WVD + k] : 0.0;
        Bl[kb+jj][ra] = (k < WVD) ? (double)Wih[(size_t)wrow*IND + EMB + k] : 0.0;
      }
    }
    __syncthreads();
    #pragma unroll 2
    for (int k=0;k<32;++k){
      double av[8], bv[8];
      #pragma unroll
      for (int i=0;i<8;++i) av[i] = Al[k][ty*8+i];
      #pragma unroll
      for (int j=0;j<8;++j) bv[j] = Bl[k][tx + 16*j];
      #pragma unroll
      for (int i=0;i<8;++i)
        #pragma unroll
        for (int j=0;j<8;++j) acc[i][j] += av[i]*bv[j];
    }
    __syncthreads();
  }

  // biases per (gate, v): unit u = u0 + tx + 16*v
  double bsum[4][2];
  #pragma unroll
  for (int g=0;g<4;++g)
    #pragma unroll
    for (int v=0;v<2;++v){
      int col = g*HID + u0 + tx + 16*v;
      bsum[g][v] = (double)bih[col] + (double)bhh[col];
    }

  #pragma unroll
  for (int i=0;i<8;++i){
    int r = r0 + ty*8 + i;
    int e = idx[r];
    const double* Er = E + (size_t)e*G4;
    #pragma unroll
    for (int v=0;v<2;++v){
      int u = u0 + tx + 16*v;
      double pi = acc[i][0+v] + Er[0*HID+u] + bsum[0][v];
      double pf = acc[i][2+v] + Er[1*HID+u] + bsum[1][v];
      double pg = acc[i][4+v] + Er[2*HID+u] + bsum[2][v];
      double po = acc[i][6+v] + Er[3*HID+u] + bsum[3][v];
      double co = cst[(size_t)r*HID + u];
      double cn = dsig(pf)*co + dsig(pi)*dtanh_(pg);
      double hn = dsig(po)*dtanh_(cn);
      cst[(size_t)r*HID + u]  = cn;
      hout[(size_t)r*HID + u] = hn;
    }
  }
}

// logits (f64) + softmax top-1 + argmax + next idx. 4 rows/block, chunk-relative.
__global__ __launch_bounds__(256) void logits_f64(
    const double* __restrict__ h, const float* __restrict__ Wlin,
    const float* __restrict__ blin, int* __restrict__ idx,
    float* __restrict__ outp, float* __restrict__ outi)
{
  __shared__ double hl[4][1024];
  __shared__ double ll[4][264];
  const int r0 = blockIdx.x*4;
  const int tid = threadIdx.x;
  #pragma unroll
  for (int i=0;i<8;++i){
    int fi = tid + 256*i;                  // double2 index, 2048 total
    int rr = fi >> 9;                      // 512 double2 per row
    int kk = (fi & 511) << 1;
    *(double2*)&hl[rr][kk] = *(const double2*)(h + (size_t)(r0+rr)*HID + kk);
  }
  __syncthreads();
  for (int c0 = 0; c0 < VOC; c0 += 256){
    int col = c0 + tid;
    if (col < VOC){
      double a[4];
      double bl = (double)blin[col];
      #pragma unroll
      for (int r=0;r<4;++r) a[r] = bl;
      const float* wr = Wlin + (size_t)col*HID;
      for (int k=0;k<HID;k+=4){
        float4 w = *(const float4*)(wr+k);
        double w0=w.x,w1=w.y,w2=w.z,w3=w.w;
        #pragma unroll
        for (int r=0;r<4;++r){
          a[r] += hl[r][k]*w0 + hl[r][k+1]*w1 + hl[r][k+2]*w2 + hl[r][k+3]*w3;
        }
      }
      #pragma unroll
      for (int r=0;r<4;++r) ll[r][col] = a[r];
    }
  }
  __syncthreads();
  const int rr = tid >> 6, sub = tid & 63;
  double m = -INFINITY; int am = 0;
  #pragma unroll
  for (int t=0;t<5;++t){
    int col = sub + 64*t;
    if (col < VOC){
      double v = ll[rr][col];
      if (v > m){ m = v; am = col; }
    }
  }
  #pragma unroll
  for (int d=1; d<64; d<<=1){
    double om = __shfl_xor(m, d, 64);
    int   oa = __shfl_xor(am, d, 64);
    if (om > m || (om == m && oa < am)){ m = om; am = oa; }
  }
  double s = 0.0;
  #pragma unroll
  for (int t=0;t<5;++t){
    int col = sub + 64*t;
    if (col < VOC) s += exp(ll[rr][col] - m);
  }
  #pragma unroll
  for (int d=1; d<64; d<<=1) s += __shfl_xor(s, d, 64);
  if (sub == 0){
    int r = r0 + rr;
    idx[r]  = am;
    outp[r] = (float)(1.0/s);
    outi[r] = (float)am;
  }
}

// ======================= f32 fallback path =======================

__global__ __launch_bounds__(256) void ekernel(const float* __restrict__ emb,
                                               const float* __restrict__ Wih,
                                               float* __restrict__ E){
  __shared__ float elds[ETT][EMB];
  const int tid = threadIdx.x;
  const int n  = blockIdx.x*256 + tid;
  const int t0 = blockIdx.y*ETT;
  #pragma unroll
  for (int i = 0; i < 8; ++i){
    int fi = tid + 256*i;
    int tt = fi >> 7;
    int kk = (fi & 127) << 2;
    float4 v = make_float4(0.f,0.f,0.f,0.f);
    if (t0+tt < VOC) v = *(const float4*)(emb + (size_t)(t0+tt)*EMB + kk);
    *(float4*)&elds[tt][kk] = v;
  }
  __syncthreads();
  float acc[ETT];
  #pragma unroll
  for (int tt=0;tt<ETT;++tt) acc[tt]=0.f;
  const float* wr = Wih + (size_t)n*IND;
  for (int k=0;k<EMB;k+=4){
    float4 w = *(const float4*)(wr + k);
    #pragma unroll
    for (int tt=0;tt<ETT;++tt){
      float4 e = *(const float4*)&elds[tt][k];
      acc[tt] += e.x*w.x + e.y*w.y + e.z*w.z + e.w*w.w;
    }
  }
  #pragma unroll
  for (int tt=0;tt<ETT;++tt){
    int t = t0+tt;
    if (t < VOC) E[(size_t)t*G4 + n] = acc[tt];
  }
}

__global__ __launch_bounds__(256) void gates_kernel(
    const float* __restrict__ hin, float* __restrict__ hout,
    float* __restrict__ cst, const int* __restrict__ idx,
    const float* __restrict__ E,
    const float* __restrict__ Whh, const float* __restrict__ Wih,
    const float* __restrict__ wv,
    const float* __restrict__ bih, const float* __restrict__ bhh,
    int nht)
{
  __shared__ float Al[32][132];
  __shared__ float Bl[32][132];
  const int tid = threadIdx.x;
  const int r0 = blockIdx.x * 128;
  const int u0 = blockIdx.y * 32;
  const int tx = tid & 15, ty = tid >> 4;
  float acc[8][8];
  #pragma unroll
  for (int i=0;i<8;++i)
    #pragma unroll
    for (int j=0;j<8;++j) acc[i][j]=0.f;

  const int nwt = 10;
  const int ra = tid >> 1;
  const int kb = (tid & 1) * 16;
  const int wrow = (ra >> 5)*HID + u0 + (ra & 31);

  for (int t = 0; t < nht + nwt; ++t){
    if (t < nht){
      int k0 = t*32;
      const float* s0 = hin + (size_t)(r0+ra)*HID + k0 + kb;
      #pragma unroll
      for (int jj=0;jj<4;++jj){
        float4 v = *(const float4*)(s0 + 4*jj);
        Al[kb+4*jj  ][ra]=v.x; Al[kb+4*jj+1][ra]=v.y;
        Al[kb+4*jj+2][ra]=v.z; Al[kb+4*jj+3][ra]=v.w;
      }
      const float* s1 = Whh + (size_t)wrow*HID + k0 + kb;
      #pragma unroll
      for (int jj=0;jj<4;++jj){
        float4 w = *(const float4*)(s1 + 4*jj);
        Bl[kb+4*jj  ][ra]=w.x; Bl[kb+4*jj+1][ra]=w.y;
        Bl[kb+4*jj+2][ra]=w.z; Bl[kb+4*jj+3][ra]=w.w;
      }
    } else {
      int k0 = (t - nht)*32;
      #pragma unroll
      for (int jj=0;jj<16;++jj){
        int k = k0 + kb + jj;
        Al[kb+jj][ra] = (k < WVD) ? wv[(size_t)(r0+ra)*WVD + k] : 0.f;
        Bl[kb+jj][ra] = (k < WVD) ? Wih[(size_t)wrow*IND + EMB + k] : 0.f;
      }
    }
    __syncthreads();
    #pragma unroll 4
    for (int k=0;k<32;++k){
      float av[8], bv[8];
      #pragma unroll
      for (int i=0;i<8;++i) av[i] = Al[k][ty*8+i];
      #pragma unroll
      for (int j=0;j<8;++j) bv[j] = Bl[k][tx + 16*j];
      #pragma unroll
      for (int i=0;i<8;++i)
        #pragma unroll
        for (int j=0;j<8;++j) acc[i][j] += av[i]*bv[j];
    }
    __syncthreads();
  }

  float bsum[4][2];
  #pragma unroll
  for (int g=0;g<4;++g)
    #pragma unroll
    for (int v=0;v<2;++v){
      int col = g*HID + u0 + tx + 16*v;
      bsum[g][v] = bih[col] + bhh[col];
    }

  #pragma unroll
  for (int i=0;i<8;++i){
    int r = r0 + ty*8 + i;
    int e = idx[r];
    const float* Er = E + (size_t)e*G4;
    #pragma unroll
    for (int v=0;v<2;++v){
      int u = u0 + tx + 16*v;
      float pi = acc[i][0+v] + Er[0*HID+u] + bsum[0][v];
      float pf = acc[i][2+v] + Er[1*HID+u] + bsum[1][v];
      float pg = acc[i][4+v] + Er[2*HID+u] + bsum[2][v];
      float po = acc[i][6+v] + Er[3*HID+u] + bsum[3][v];
      float co = cst[(size_t)r*HID + u];
      float cn = sigf(pf)*co + sigf(pi)*tanhf(pg);
      float hn = sigf(po)*tanhf(cn);
      cst[(size_t)r*HID + u]  = cn;
      hout[(size_t)r*HID + u] = hn;
    }
  }
}

__global__ __launch_bounds__(256) void logits_kernel(
    const float* __restrict__ h, const float* __restrict__ Wlin,
    const float* __restrict__ blin, int* __restrict__ idx,
    float* __restrict__ outp, float* __restrict__ outi)
{
  __shared__ float hl[8][1024];
  __shared__ float ll[8][264];
  const int r0 = blockIdx.x*8;
  const int tid = threadIdx.x;
  #pragma unroll
  for (int i=0;i<8;++i){
    int fi = tid + 256*i;
    int rr = fi >> 8, kk = (fi & 255) << 2;
    *(float4*)&hl[rr][kk] = *(const float4*)(h + (size_t)(r0+rr)*HID + kk);
  }
  __syncthreads();
  for (int c0 = 0; c0 < VOC; c0 += 256){
    int col = c0 + tid;
    if (col < VOC){
      float a[8];
      #pragma unroll
      for (int r=0;r<8;++r) a[r] = blin[col];
      const float* wr = Wlin + (size_t)col*HID;
      for (int k=0;k<HID;k+=4){
        float4 w = *(const float4*)(wr+k);
        #pragma unroll
        for (int r=0;r<8;++r){
          float4 hv = *(const float4*)&hl[r][k];
          a[r] += hv.x*w.x + hv.y*w.y + hv.z*w.z + hv.w*w.w;
        }
      }
      #pragma unroll
      for (int r=0;r<8;++r) ll[r][col] = a[r];
    }
  }
  __syncthreads();
  const int rr = tid >> 5, sub = tid & 31;
  float m = -INFINITY; int am = 0;
  for (int t=0;t<9;++t){
    int col = sub + 32*t;
    if (col < VOC){
      float v = ll[rr][col];
      if (v > m){ m = v; am = col; }
    }
  }
  #pragma unroll
  for (int d=1; d<32; d<<=1){
    float om = __shfl_xor(m, d, 32);
    int   oa = __shfl_xor(am, d, 32);
    if (om > m || (om == m && oa < am)){ m = om; am = oa; }
  }
  float s = 0.f;
  for (int t=0;t<9;++t){
    int col = sub + 32*t;
    if (col < VOC) s += expf(ll[rr][col] - m);
  }
  #pragma unroll
  for (int d=1; d<32; d<<=1) s += __shfl_xor(s, d, 32);
  if (sub == 0){
    int r = r0 + rr;
    idx[r]  = am;
    outp[r] = 1.0f / s;
    outi[r] = (float)am;
  }
}

// ======================= launch =======================

extern "C" void kernel_launch(void* const* d_in, const int* in_sizes, int n_in,
                              void* d_out, int out_size, void* d_ws, size_t ws_size,
                              hipStream_t stream){
  const float* wv   = (const float*)d_in[0];
  const float* emb  = (const float*)d_in[1];
  const float* Wih  = (const float*)d_in[2];
  const float* Whh  = (const float*)d_in[3];
  const float* bih  = (const float*)d_in[4];
  const float* bhh  = (const float*)d_in[5];
  const float* Wlin = (const float*)d_in[6];
  const float* blin = (const float*)d_in[7];
  float* out = (float*)d_out;

  char* w = (char*)d_ws;
  size_t off = 0;
  auto alloc = [&](size_t bytes) -> void* {
    void* p = w + off; off += (bytes + 255) & ~(size_t)255; return p;
  };

  // adaptive row-chunked f64 path: rows are independent -> reuse h/c buffers
  size_t base_need = ((size_t)VOC*G4*8 + 256) + ((size_t)BS*4 + 256);
  int R = 0;
  for (int r = BS; r >= 256; r >>= 1){
    if (base_need + 3*((size_t)r*HID*8 + 256) <= ws_size){ R = r; break; }
  }

  if (R > 0){
    double* Ed  = (double*)alloc((size_t)VOC*G4*8);
    int*    idx = (int*)   alloc((size_t)BS*4);
    double* h0  = (double*)alloc((size_t)R*HID*8);
    double* h1  = (double*)alloc((size_t)R*HID*8);
    double* cd  = (double*)alloc((size_t)R*HID*8);

    hipMemsetAsync(idx, 0, (size_t)BS*4, stream);
    ekernel_f64<<<dim3(16,17),256,0,stream>>>(emb, Wih, Ed);

    for (int c0 = 0; c0 < BS; c0 += R){
      hipMemsetAsync(cd, 0, (size_t)R*HID*8, stream);
      double* hb[2] = {h0, h1};
      for (int s = 0; s < NST; ++s){
        gates_f64<<<dim3(R/128, HID/32),256,0,stream>>>(
            hb[s&1], hb[(s+1)&1], cd, idx + c0, Ed,
            Whh, Wih, wv + (size_t)c0*WVD, bih, bhh, (s==0) ? 0 : HID/32);
        logits_f64<<<R/4,256,0,stream>>>(
            hb[(s+1)&1], Wlin, blin, idx + c0,
            out + (size_t)s*BS + c0, out + (size_t)NST*BS + (size_t)s*BS + c0);
      }
    }
    return;
  }

  // f32 fallback (only if workspace is implausibly small)
  float* h0  = (float*)alloc((size_t)BS*HID*4);
  float* h1  = (float*)alloc((size_t)BS*HID*4);
  float* c   = (float*)alloc((size_t)BS*HID*4);
  int*   idx = (int*)  alloc((size_t)BS*4);
  float* E   = (float*)alloc((size_t)VOC*G4*4);

  hipMemsetAsync(c,  0, (size_t)BS*HID*4, stream);
  hipMemsetAsync(idx,0, (size_t)BS*4,     stream);

  ekernel<<<dim3(16,17),256,0,stream>>>(emb, Wih, E);

  float* hb[2] = {h0, h1};
  for (int s = 0; s < NST; ++s){
    gates_kernel<<<dim3(BS/128, HID/32),256,0,stream>>>(
        hb[s&1], hb[(s+1)&1], c, idx, E,
        Whh, Wih, wv, bih, bhh, (s==0) ? 0 : HID/32);
    logits_kernel<<<BS/8,256,0,stream>>>(
        hb[(s+1)&1], Wlin, blin, idx,
        out + (size_t)s*BS, out + (size_t)NST*BS + (size_t)s*BS);
  }
}

// Round 4
// 51400.494 us; speedup vs baseline: 1.3359x; 1.3359x over previous
//
#include <hip/hip_runtime.h>
#include <math.h>

#define BS   16384
#define HID  1024
#define G4   4096
#define EMB  512
#define WVD  300
#define IND  812
#define VOC  258
#define NST  14

__device__ __forceinline__ double dsig(double x){ return 1.0/(1.0+exp(-x)); }
__device__ __forceinline__ double dtanh_(double x){
  double ax = fabs(x);
  double e = exp(-2.0*ax);
  double t = (1.0-e)/(1.0+e);
  return x < 0.0 ? -t : t;
}

// ---------------- E = emb @ W_ih[:, :512].T -> f64 [VOC][G4] ----------------
#define ETT 16
__global__ __launch_bounds__(256) void ekernel_f64(const float* __restrict__ emb,
                                                   const float* __restrict__ Wih,
                                                   double* __restrict__ E){
  __shared__ float elds[ETT][EMB];
  const int tid = threadIdx.x;
  const int n  = blockIdx.x*256 + tid;      // 0..4095
  const int t0 = blockIdx.y*ETT;
  #pragma unroll
  for (int i = 0; i < 8; ++i){
    int fi = tid + 256*i;
    int tt = fi >> 7;
    int kk = (fi & 127) << 2;
    float4 v = make_float4(0.f,0.f,0.f,0.f);
    if (t0+tt < VOC) v = *(const float4*)(emb + (size_t)(t0+tt)*EMB + kk);
    *(float4*)&elds[tt][kk] = v;
  }
  __syncthreads();
  double acc[ETT];
  #pragma unroll
  for (int tt=0;tt<ETT;++tt) acc[tt]=0.0;
  const float* wr = Wih + (size_t)n*IND;
  for (int k=0;k<EMB;k+=4){
    float4 w = *(const float4*)(wr + k);
    double w0=w.x, w1=w.y, w2=w.z, w3=w.w;
    #pragma unroll
    for (int tt=0;tt<ETT;++tt){
      float4 e = *(const float4*)&elds[tt][k];
      acc[tt] += (double)e.x*w0 + (double)e.y*w1 + (double)e.z*w2 + (double)e.w*w3;
    }
  }
  #pragma unroll
  for (int tt=0;tt<ETT;++tt){
    int t = t0+tt;
    if (t < VOC) E[(size_t)t*G4 + n] = acc[tt];
  }
}

// ---------------- base = wv @ Wih[:,512:].T + b_ih + b_hh -> f64 [R][G4] ----------------
// tile 64 rows x 64 cols, K=300 in 19 k-tiles of 16
__global__ __launch_bounds__(256) void base_f64(const float* __restrict__ wv,
                                                const float* __restrict__ Wih,
                                                const float* __restrict__ bih,
                                                const float* __restrict__ bhh,
                                                double* __restrict__ base){
  __shared__ double Al[16][68];
  __shared__ double Bl[16][68];
  const int tid = threadIdx.x;
  const int r0 = blockIdx.x*64, n0 = blockIdx.y*64;
  const int tx = tid & 15, ty = tid >> 4;
  double acc[4][4];
  #pragma unroll
  for (int i=0;i<4;++i)
    #pragma unroll
    for (int j=0;j<4;++j) acc[i][j]=0.0;

  const int ra = tid >> 2, kb = (tid & 3) * 4;
  for (int t = 0; t < 19; ++t){
    int k0 = t*16;
    #pragma unroll
    for (int j=0;j<4;++j){
      int k = k0 + kb + j;
      Al[kb+j][ra] = (k < WVD) ? (double)wv[(size_t)(r0+ra)*WVD + k] : 0.0;
      Bl[kb+j][ra] = (k < WVD) ? (double)Wih[(size_t)(n0+ra)*IND + EMB + k] : 0.0;
    }
    __syncthreads();
    #pragma unroll
    for (int k=0;k<16;++k){
      double av[4], bv[4];
      #pragma unroll
      for (int i=0;i<4;++i) av[i] = Al[k][ty*4+i];
      #pragma unroll
      for (int j=0;j<4;++j) bv[j] = Bl[k][tx+16*j];
      #pragma unroll
      for (int i=0;i<4;++i)
        #pragma unroll
        for (int j=0;j<4;++j) acc[i][j] += av[i]*bv[j];
    }
    __syncthreads();
  }
  #pragma unroll
  for (int i=0;i<4;++i){
    int r = r0 + ty*4 + i;
    #pragma unroll
    for (int j=0;j<4;++j){
      int n = n0 + tx + 16*j;
      base[(size_t)r*G4 + n] = acc[i][j] + (double)bih[n] + (double)bhh[n];
    }
  }
}

// ---------------- fused gates GEMM (f64) + LSTM cell ----------------
// block: 128 rows x 64 gate-cols (4 gates x 16 units). 256 thr, acc[8][4].
// B col c (0..63): gate g = c>>4, unit = u0 + (c&15). thread cols: tx + 16*j -> gate j, unit u0+tx.
__global__ __launch_bounds__(256) void gates_f64(
    const double* __restrict__ hin, double* __restrict__ hout,
    double* __restrict__ cst, const int* __restrict__ idx,
    const double* __restrict__ E, const double* __restrict__ base,
    const float* __restrict__ Whh, const float* __restrict__ Wih,
    const float* __restrict__ wv,
    const float* __restrict__ bih, const float* __restrict__ bhh,
    int nht, int nwt)
{
  __shared__ double Al[16][132];
  __shared__ double Bl[16][68];
  const int tid = threadIdx.x;
  const int r0 = blockIdx.x * 128;
  const int u0 = blockIdx.y * 16;
  const int tx = tid & 15, ty = tid >> 4;
  double acc[8][4];
  #pragma unroll
  for (int i=0;i<8;++i)
    #pragma unroll
    for (int j=0;j<4;++j) acc[i][j]=0.0;

  const int ra  = tid >> 1, kb8 = (tid & 1) * 8;   // A staging: row ra, 8 k
  const int cb  = tid >> 2, kb4 = (tid & 3) * 4;   // B staging: col cb, 4 k
  const int wrow = (cb >> 4)*HID + u0 + (cb & 15); // W row for B col cb

  for (int t = 0; t < nht + nwt; ++t){
    if (t < nht){
      int k0 = t*16;
      const double* s0 = hin + (size_t)(r0+ra)*HID + k0 + kb8;
      double2 v0 = *(const double2*)(s0+0);
      double2 v1 = *(const double2*)(s0+2);
      double2 v2 = *(const double2*)(s0+4);
      double2 v3 = *(const double2*)(s0+6);
      Al[kb8+0][ra]=v0.x; Al[kb8+1][ra]=v0.y;
      Al[kb8+2][ra]=v1.x; Al[kb8+3][ra]=v1.y;
      Al[kb8+4][ra]=v2.x; Al[kb8+5][ra]=v2.y;
      Al[kb8+6][ra]=v3.x; Al[kb8+7][ra]=v3.y;
      float4 w = *(const float4*)(Whh + (size_t)wrow*HID + k0 + kb4);
      Bl[kb4+0][cb] = (double)w.x;
      Bl[kb4+1][cb] = (double)w.y;
      Bl[kb4+2][cb] = (double)w.z;
      Bl[kb4+3][cb] = (double)w.w;
    } else {
      int k0 = (t - nht)*16;
      #pragma unroll
      for (int j=0;j<8;++j){
        int k = k0 + kb8 + j;
        Al[kb8+j][ra] = (k < WVD) ? (double)wv[(size_t)(r0+ra)*WVD + k] : 0.0;
      }
      #pragma unroll
      for (int j=0;j<4;++j){
        int k = k0 + kb4 + j;
        Bl[kb4+j][cb] = (k < WVD) ? (double)Wih[(size_t)wrow*IND + EMB + k] : 0.0;
      }
    }
    __syncthreads();
    #pragma unroll
    for (int k=0;k<16;++k){
      double av[8], bv[4];
      #pragma unroll
      for (int i=0;i<8;++i) av[i] = Al[k][ty*8+i];
      #pragma unroll
      for (int j=0;j<4;++j) bv[j] = Bl[k][tx + 16*j];
      #pragma unroll
      for (int i=0;i<8;++i)
        #pragma unroll
        for (int j=0;j<4;++j) acc[i][j] += av[i]*bv[j];
    }
    __syncthreads();
  }

  // epilogue: LSTM cell. thread: rows r0+ty*8+i, single unit u0+tx, all 4 gates.
  const int u = u0 + tx;
  #pragma unroll
  for (int i=0;i<8;++i){
    int r = r0 + ty*8 + i;
    int tok = idx[r];
    const double* Er = E + (size_t)tok*G4;
    double pre[4];
    if (base){
      const double* Br = base + (size_t)r*G4;
      #pragma unroll
      for (int g=0;g<4;++g) pre[g] = acc[i][g] + Er[g*HID+u] + Br[g*HID+u];
    } else {
      #pragma unroll
      for (int g=0;g<4;++g) pre[g] = acc[i][g] + Er[g*HID+u]
                                   + (double)bih[g*HID+u] + (double)bhh[g*HID+u];
    }
    double co = cst[(size_t)r*HID + u];
    double cn = dsig(pre[1])*co + dsig(pre[0])*dtanh_(pre[2]);
    double hn = dsig(pre[3])*dtanh_(cn);
    cst[(size_t)r*HID + u]  = cn;
    hout[(size_t)r*HID + u] = hn;
  }
}

// ---------------- logits GEMM (f64): lbuf[r][n] = h.Wlin^T + blin ----------------
// tile 64 rows x 64 cols, K=1024, k-tile 16. grid.y=5 (320 padded cols, masked).
__global__ __launch_bounds__(256) void logits_gemm_f64(
    const double* __restrict__ h, const float* __restrict__ Wlin,
    const float* __restrict__ blin, double* __restrict__ lbuf)
{
  __shared__ double Al[16][68];
  __shared__ double Bl[16][68];
  const int tid = threadIdx.x;
  const int r0 = blockIdx.x*64, n0 = blockIdx.y*64;
  const int tx = tid & 15, ty = tid >> 4;
  double acc[4][4];
  #pragma unroll
  for (int i=0;i<4;++i)
    #pragma unroll
    for (int j=0;j<4;++j) acc[i][j]=0.0;

  const int ra = tid >> 2, kb = (tid & 3) * 4;
  const int wr = n0 + ra;
  const bool wok = (wr < VOC);
  for (int t = 0; t < 64; ++t){
    int k0 = t*16;
    const double* s0 = h + (size_t)(r0+ra)*HID + k0 + kb;
    double2 a0 = *(const double2*)(s0+0);
    double2 a1 = *(const double2*)(s0+2);
    Al[kb+0][ra]=a0.x; Al[kb+1][ra]=a0.y;
    Al[kb+2][ra]=a1.x; Al[kb+3][ra]=a1.y;
    if (wok){
      float4 w = *(const float4*)(Wlin + (size_t)wr*HID + k0 + kb);
      Bl[kb+0][ra] = (double)w.x;
      Bl[kb+1][ra] = (double)w.y;
      Bl[kb+2][ra] = (double)w.z;
      Bl[kb+3][ra] = (double)w.w;
    } else {
      Bl[kb+0][ra]=0.0; Bl[kb+1][ra]=0.0; Bl[kb+2][ra]=0.0; Bl[kb+3][ra]=0.0;
    }
    __syncthreads();
    #pragma unroll
    for (int k=0;k<16;++k){
      double av[4], bv[4];
      #pragma unroll
      for (int i=0;i<4;++i) av[i] = Al[k][ty*4+i];
      #pragma unroll
      for (int j=0;j<4;++j) bv[j] = Bl[k][tx+16*j];
      #pragma unroll
      for (int i=0;i<4;++i)
        #pragma unroll
        for (int j=0;j<4;++j) acc[i][j] += av[i]*bv[j];
    }
    __syncthreads();
  }
  #pragma unroll
  for (int i=0;i<4;++i){
    int r = r0 + ty*4 + i;
    #pragma unroll
    for (int j=0;j<4;++j){
      int n = n0 + tx + 16*j;
      if (n < VOC) lbuf[(size_t)r*HID + n] = acc[i][j] + (double)blin[n];
    }
  }
}

// ---------------- softmax top-1 + argmax + next idx ----------------
// 4 rows/block (1 wave per row). lbuf stride = HID doubles.
__global__ __launch_bounds__(256) void argmax_f64(
    const double* __restrict__ lbuf, int* __restrict__ idx,
    float* __restrict__ outp, float* __restrict__ outi)
{
  const int tid = threadIdx.x;
  const int r = blockIdx.x*4 + (tid >> 6);
  const int lane = tid & 63;
  const double* lr = lbuf + (size_t)r*HID;
  double m = -INFINITY; int am = 0;
  #pragma unroll
  for (int t=0;t<5;++t){
    int col = lane + 64*t;
    if (col < VOC){
      double v = lr[col];
      if (v > m){ m = v; am = col; }
    }
  }
  #pragma unroll
  for (int d=1; d<64; d<<=1){
    double om = __shfl_xor(m, d, 64);
    int   oa = __shfl_xor(am, d, 64);
    if (om > m || (om == m && oa < am)){ m = om; am = oa; }
  }
  double s = 0.0;
  #pragma unroll
  for (int t=0;t<5;++t){
    int col = lane + 64*t;
    if (col < VOC) s += exp(lr[col] - m);
  }
  #pragma unroll
  for (int d=1; d<64; d<<=1) s += __shfl_xor(s, d, 64);
  if (lane == 0){
    idx[r]  = am;
    outp[r] = (float)(1.0/s);
    outi[r] = (float)am;
  }
}

// ======================= launch =======================

extern "C" void kernel_launch(void* const* d_in, const int* in_sizes, int n_in,
                              void* d_out, int out_size, void* d_ws, size_t ws_size,
                              hipStream_t stream){
  const float* wv   = (const float*)d_in[0];
  const float* emb  = (const float*)d_in[1];
  const float* Wih  = (const float*)d_in[2];
  const float* Whh  = (const float*)d_in[3];
  const float* bih  = (const float*)d_in[4];
  const float* bhh  = (const float*)d_in[5];
  const float* Wlin = (const float*)d_in[6];
  const float* blin = (const float*)d_in[7];
  float* out = (float*)d_out;

  char* w = (char*)d_ws;
  size_t off = 0;
  auto al = [](size_t b){ return (b + 255) & ~(size_t)255; };
  auto alloc = [&](size_t bytes) -> void* {
    void* p = w + off; off += al(bytes); return p;
  };

  const size_t fixed = al((size_t)VOC*G4*8) + al((size_t)BS*4);

  // tier A: base precompute (preferred). tier B: no base, wv folded into gates.
  int R = 0; bool useBase = false;
  for (int r = 4096; r >= 1024; r >>= 1){
    if (fixed + 3*al((size_t)r*HID*8) + al((size_t)r*G4*8) <= ws_size){ R = r; useBase = true; break; }
  }
  if (!R){
    for (int r = 8192; r >= 256; r >>= 1){
      if (fixed + 3*al((size_t)r*HID*8) <= ws_size){ R = r; break; }
    }
  }
  if (!R) return; // workspace implausibly small

  double* Ed  = (double*)alloc((size_t)VOC*G4*8);
  int*    idx = (int*)   alloc((size_t)BS*4);
  double* h0  = (double*)alloc((size_t)R*HID*8);
  double* h1  = (double*)alloc((size_t)R*HID*8);
  double* cd  = (double*)alloc((size_t)R*HID*8);
  double* base = useBase ? (double*)alloc((size_t)R*G4*8) : nullptr;

  hipMemsetAsync(idx, 0, (size_t)BS*4, stream);
  ekernel_f64<<<dim3(16,17),256,0,stream>>>(emb, Wih, Ed);

  for (int c0 = 0; c0 < BS; c0 += R){
    if (useBase)
      base_f64<<<dim3(R/64, 64),256,0,stream>>>(wv + (size_t)c0*WVD, Wih, bih, bhh, base);
    hipMemsetAsync(cd, 0, (size_t)R*HID*8, stream);
    double* hb[2] = {h0, h1};
    for (int s = 0; s < NST; ++s){
      gates_f64<<<dim3(R/128, 64),256,0,stream>>>(
          hb[s&1], hb[(s+1)&1], cd, idx + c0, Ed, base,
          Whh, Wih, wv + (size_t)c0*WVD, bih, bhh,
          (s==0) ? 0 : HID/16, useBase ? 0 : 19);
      // logits written into the now-dead hb[s&1] buffer (stride HID)
      logits_gemm_f64<<<dim3(R/64, 5),256,0,stream>>>(
          hb[(s+1)&1], Wlin, blin, hb[s&1]);
      argmax_f64<<<R/4,256,0,stream>>>(
          hb[s&1], idx + c0,
          out + (size_t)s*BS + c0, out + (size_t)NST*BS + (size_t)s*BS + c0);
    }
  }
}

// Round 6
// 46548.001 us; speedup vs baseline: 1.4751x; 1.1042x over previous
//
#include <hip/hip_runtime.h>
#include <math.h>

#define BS   16384
#define HID  1024
#define G4   4096
#define EMB  512
#define WVD  300
#define IND  812
#define VOC  258
#define NST  14

__device__ __forceinline__ double dsig(double x){ return 1.0/(1.0+exp(-x)); }
__device__ __forceinline__ double dtanh_(double x){
  double ax = fabs(x);
  double e = exp(-2.0*ax);
  double t = (1.0-e)/(1.0+e);
  return x < 0.0 ? -t : t;
}

// ---------------- E = emb @ W_ih[:, :512].T -> f64 [VOC][G4] ----------------
#define ETT 16
__global__ __launch_bounds__(256) void ekernel_f64(const float* __restrict__ emb,
                                                   const float* __restrict__ Wih,
                                                   double* __restrict__ E){
  __shared__ float elds[ETT][EMB];
  const int tid = threadIdx.x;
  const int n  = blockIdx.x*256 + tid;      // 0..4095
  const int t0 = blockIdx.y*ETT;
  #pragma unroll
  for (int i = 0; i < 8; ++i){
    int fi = tid + 256*i;
    int tt = fi >> 7;
    int kk = (fi & 127) << 2;
    float4 v = make_float4(0.f,0.f,0.f,0.f);
    if (t0+tt < VOC) v = *(const float4*)(emb + (size_t)(t0+tt)*EMB + kk);
    *(float4*)&elds[tt][kk] = v;
  }
  __syncthreads();
  double acc[ETT];
  #pragma unroll
  for (int tt=0;tt<ETT;++tt) acc[tt]=0.0;
  const float* wr = Wih + (size_t)n*IND;
  for (int k=0;k<EMB;k+=4){
    float4 w = *(const float4*)(wr + k);
    double w0=w.x, w1=w.y, w2=w.z, w3=w.w;
    #pragma unroll
    for (int tt=0;tt<ETT;++tt){
      float4 e = *(const float4*)&elds[tt][k];
      acc[tt] += (double)e.x*w0 + (double)e.y*w1 + (double)e.z*w2 + (double)e.w*w3;
    }
  }
  #pragma unroll
  for (int tt=0;tt<ETT;++tt){
    int t = t0+tt;
    if (t < VOC) E[(size_t)t*G4 + n] = acc[tt];
  }
}

// ---------------- base = wv @ Wih[:,512:].T + b_ih + b_hh -> f64 [R][G4] ----------------
__global__ __launch_bounds__(256) void base_f64(const float* __restrict__ wv,
                                                const float* __restrict__ Wih,
                                                const float* __restrict__ bih,
                                                const float* __restrict__ bhh,
                                                double* __restrict__ base){
  __shared__ double Al[16][68];
  __shared__ double Bl[16][68];
  const int tid = threadIdx.x;
  const int r0 = blockIdx.x*64, n0 = blockIdx.y*64;
  const int tx = tid & 15, ty = tid >> 4;
  double acc[4][4];
  #pragma unroll
  for (int i=0;i<4;++i)
    #pragma unroll
    for (int j=0;j<4;++j) acc[i][j]=0.0;

  const int ra = tid >> 2, kb = (tid & 3) * 4;
  for (int t = 0; t < 19; ++t){
    int k0 = t*16;
    #pragma unroll
    for (int j=0;j<4;++j){
      int k = k0 + kb + j;
      Al[kb+j][ra] = (k < WVD) ? (double)wv[(size_t)(r0+ra)*WVD + k] : 0.0;
      Bl[kb+j][ra] = (k < WVD) ? (double)Wih[(size_t)(n0+ra)*IND + EMB + k] : 0.0;
    }
    __syncthreads();
    #pragma unroll
    for (int k=0;k<16;++k){
      double av[4], bv[4];
      #pragma unroll
      for (int i=0;i<4;++i) av[i] = Al[k][ty*4+i];
      #pragma unroll
      for (int j=0;j<4;++j) bv[j] = Bl[k][tx+16*j];
      #pragma unroll
      for (int i=0;i<4;++i)
        #pragma unroll
        for (int j=0;j<4;++j) acc[i][j] += av[i]*bv[j];
    }
    __syncthreads();
  }
  #pragma unroll
  for (int i=0;i<4;++i){
    int r = r0 + ty*4 + i;
    #pragma unroll
    for (int j=0;j<4;++j){
      int n = n0 + tx + 16*j;
      base[(size_t)r*G4 + n] = acc[i][j] + (double)bih[n] + (double)bhh[n];
    }
  }
}

// ---------------- fused gates GEMM (f64, acc 8x8) + LSTM cell ----------------
// block 256 thr. tile: 128 rows x 128 gate-cols (4 gates x 32 units), u0 = blockIdx.y*32.
// col c in [0,128): gate g = c>>5, unit = u0 + (c&31).
// thread (tx,ty): rows r0+ty*8+i; cols tx+16*j -> gate j>>1, unit u0+tx+16*(j&1).
__global__ __launch_bounds__(256) void gates_v2(
    const double* __restrict__ hin, double* __restrict__ hout,
    double* __restrict__ cst, const int* __restrict__ idx,
    const double* __restrict__ E, const double* __restrict__ base,
    const float* __restrict__ Whh, const float* __restrict__ Wih,
    const float* __restrict__ wv,
    const float* __restrict__ bih, const float* __restrict__ bhh,
    int nht, int nwt)
{
  __shared__ double Al[16][132];
  __shared__ double Bl[16][132];
  const int tid = threadIdx.x;
  const int r0 = blockIdx.x * 128;
  const int u0 = blockIdx.y * 32;
  const int tx = tid & 15, ty = tid >> 4;
  double acc[8][8];
  #pragma unroll
  for (int i=0;i<8;++i)
    #pragma unroll
    for (int j=0;j<8;++j) acc[i][j]=0.0;

  const int ra  = tid >> 1, kb8 = (tid & 1) * 8;   // A staging: row ra, 8 k each
  const int cb  = ra;                               // B staging: col cb, 8 k each
  const int wrow = (cb >> 5)*HID + u0 + (cb & 31);  // Whh row for B col cb

  for (int t = 0; t < nht + nwt; ++t){
    if (t < nht){
      int k0 = t*16;
      const double* s0 = hin + (size_t)(r0+ra)*HID + k0 + kb8;
      #pragma unroll
      for (int jj=0;jj<4;++jj){
        double2 v = *(const double2*)(s0 + 2*jj);
        Al[kb8+2*jj  ][ra] = v.x;
        Al[kb8+2*jj+1][ra] = v.y;
      }
      const float* s1 = Whh + (size_t)wrow*HID + k0 + kb8;
      float4 w0 = *(const float4*)(s1+0);
      float4 w1 = *(const float4*)(s1+4);
      Bl[kb8+0][cb] = (double)w0.x;
      Bl[kb8+1][cb] = (double)w0.y;
      Bl[kb8+2][cb] = (double)w0.z;
      Bl[kb8+3][cb] = (double)w0.w;
      Bl[kb8+4][cb] = (double)w1.x;
      Bl[kb8+5][cb] = (double)w1.y;
      Bl[kb8+6][cb] = (double)w1.z;
      Bl[kb8+7][cb] = (double)w1.w;
    } else {
      int k0 = (t - nht)*16;
      #pragma unroll
      for (int j=0;j<8;++j){
        int k = k0 + kb8 + j;
        Al[kb8+j][ra] = (k < WVD) ? (double)wv[(size_t)(r0+ra)*WVD + k] : 0.0;
        Bl[kb8+j][cb] = (k < WVD) ? (double)Wih[(size_t)wrow*IND + EMB + k] : 0.0;
      }
    }
    __syncthreads();
    #pragma unroll
    for (int k=0;k<16;++k){
      double av[8], bv[8];
      #pragma unroll
      for (int i=0;i<8;++i) av[i] = Al[k][ty*8+i];
      #pragma unroll
      for (int j=0;j<8;++j) bv[j] = Bl[k][tx + 16*j];
      #pragma unroll
      for (int i=0;i<8;++i)
        #pragma unroll
        for (int j=0;j<8;++j) acc[i][j] += av[i]*bv[j];
    }
    __syncthreads();
  }

  // epilogue: LSTM cell. thread: rows r0+ty*8+i, units u0+tx, u0+tx+16, all 4 gates.
  #pragma unroll
  for (int i=0;i<8;++i){
    int r = r0 + ty*8 + i;
    int tok = idx[r];
    const double* Er = E + (size_t)tok*G4;
    #pragma unroll
    for (int v=0;v<2;++v){
      int u = u0 + tx + 16*v;
      double pre[4];
      if (base){
        const double* Br = base + (size_t)r*G4;
        #pragma unroll
        for (int g=0;g<4;++g) pre[g] = acc[i][2*g+v] + Er[g*HID+u] + Br[g*HID+u];
      } else {
        #pragma unroll
        for (int g=0;g<4;++g) pre[g] = acc[i][2*g+v] + Er[g*HID+u]
                                     + (double)bih[g*HID+u] + (double)bhh[g*HID+u];
      }
      double co = cst[(size_t)r*HID + u];
      double cn = dsig(pre[1])*co + dsig(pre[0])*dtanh_(pre[2]);
      double hn = dsig(pre[3])*dtanh_(cn);
      cst[(size_t)r*HID + u]  = cn;
      hout[(size_t)r*HID + u] = hn;
    }
  }
}

// ---------------- logits partial GEMM (f64 VALU), split-K=3 ----------------
// grid (R/64, 5, 3). tile 64 rows x 64 cols. partials -> lbuf[r*HID + kk*320 + n].
__global__ __launch_bounds__(256) void logits_sk(
    const double* __restrict__ h, const float* __restrict__ Wlin,
    double* __restrict__ lbuf)
{
  __shared__ double Al[16][68];
  __shared__ double Bl[16][68];
  const int tid = threadIdx.x;
  const int r0 = blockIdx.x*64, n0 = blockIdx.y*64, kk = blockIdx.z;
  const int kt0 = (kk==0) ? 0  : (kk==1) ? 22 : 43;
  const int kt1 = (kk==0) ? 22 : (kk==1) ? 43 : 64;
  const int tx = tid & 15, ty = tid >> 4;
  double acc[4][4];
  #pragma unroll
  for (int i=0;i<4;++i)
    #pragma unroll
    for (int j=0;j<4;++j) acc[i][j]=0.0;

  const int ra = tid >> 2, kb = (tid & 3) * 4;
  const int wr = n0 + ra;
  const bool wok = (wr < VOC);
  for (int t = kt0; t < kt1; ++t){
    int k0 = t*16;
    const double* s0 = h + (size_t)(r0+ra)*HID + k0 + kb;
    double2 a0 = *(const double2*)(s0+0);
    double2 a1 = *(const double2*)(s0+2);
    Al[kb+0][ra]=a0.x; Al[kb+1][ra]=a0.y;
    Al[kb+2][ra]=a1.x; Al[kb+3][ra]=a1.y;
    if (wok){
      float4 w = *(const float4*)(Wlin + (size_t)wr*HID + k0 + kb);
      Bl[kb+0][ra] = (double)w.x;
      Bl[kb+1][ra] = (double)w.y;
      Bl[kb+2][ra] = (double)w.z;
      Bl[kb+3][ra] = (double)w.w;
    } else {
      Bl[kb+0][ra]=0.0; Bl[kb+1][ra]=0.0; Bl[kb+2][ra]=0.0; Bl[kb+3][ra]=0.0;
    }
    __syncthreads();
    #pragma unroll
    for (int k=0;k<16;++k){
      double av[4], bv[4];
      #pragma unroll
      for (int i=0;i<4;++i) av[i] = Al[k][ty*4+i];
      #pragma unroll
      for (int j=0;j<4;++j) bv[j] = Bl[k][tx+16*j];
      #pragma unroll
      for (int i=0;i<4;++i)
        #pragma unroll
        for (int j=0;j<4;++j) acc[i][j] += av[i]*bv[j];
    }
    __syncthreads();
  }
  #pragma unroll
  for (int i=0;i<4;++i){
    int r = r0 + ty*4 + i;
    #pragma unroll
    for (int j=0;j<4;++j){
      int n = n0 + tx + 16*j;                 // 0..319
      lbuf[(size_t)r*HID + kk*320 + n] = acc[i][j];
    }
  }
}

// ---------------- sum partials + bias, softmax top-1, argmax, next idx ----------------
__global__ __launch_bounds__(256) void argmax_f64(
    const double* __restrict__ lbuf, const float* __restrict__ blin,
    int* __restrict__ idx, float* __restrict__ outp, float* __restrict__ outi)
{
  const int tid = threadIdx.x;
  const int r = blockIdx.x*4 + (tid >> 6);
  const int lane = tid & 63;
  const double* lr = lbuf + (size_t)r*HID;
  double v[5];
  double m = -INFINITY; int am = 0;
  #pragma unroll
  for (int t=0;t<5;++t){
    int col = lane + 64*t;
    if (col < VOC){
      double x = ((lr[col] + lr[320+col]) + lr[640+col]) + (double)blin[col];
      v[t] = x;
      if (x > m){ m = x; am = col; }
    } else v[t] = -INFINITY;
  }
  #pragma unroll
  for (int d=1; d<64; d<<=1){
    double om = __shfl_xor(m, d, 64);
    int   oa = __shfl_xor(am, d, 64);
    if (om > m || (om == m && oa < am)){ m = om; am = oa; }
  }
  double s = 0.0;
  #pragma unroll
  for (int t=0;t<5;++t){
    int col = lane + 64*t;
    if (col < VOC) s += exp(v[t] - m);
  }
  #pragma unroll
  for (int d=1; d<64; d<<=1) s += __shfl_xor(s, d, 64);
  if (lane == 0){
    idx[r]  = am;
    outp[r] = (float)(1.0/s);
    outi[r] = (float)am;
  }
}

// ======================= launch =======================

extern "C" void kernel_launch(void* const* d_in, const int* in_sizes, int n_in,
                              void* d_out, int out_size, void* d_ws, size_t ws_size,
                              hipStream_t stream){
  const float* wv   = (const float*)d_in[0];
  const float* emb  = (const float*)d_in[1];
  const float* Wih  = (const float*)d_in[2];
  const float* Whh  = (const float*)d_in[3];
  const float* bih  = (const float*)d_in[4];
  const float* bhh  = (const float*)d_in[5];
  const float* Wlin = (const float*)d_in[6];
  const float* blin = (const float*)d_in[7];
  float* out = (float*)d_out;

  char* w = (char*)d_ws;
  size_t off = 0;
  auto al = [](size_t b){ return (b + 255) & ~(size_t)255; };
  auto alloc = [&](size_t bytes) -> void* {
    void* p = w + off; off += al(bytes); return p;
  };

  const size_t fixed = al((size_t)VOC*G4*8) + al((size_t)BS*4);

  // tier A: base precompute (preferred). tier B: no base, wv folded into gates.
  int R = 0; bool useBase = false;
  for (int r = 4096; r >= 1024; r >>= 1){
    if (fixed + 3*al((size_t)r*HID*8) + al((size_t)r*G4*8) <= ws_size){ R = r; useBase = true; break; }
  }
  if (!R){
    for (int r = 8192; r >= 256; r >>= 1){
      if (fixed + 3*al((size_t)r*HID*8) <= ws_size){ R = r; break; }
    }
  }
  if (!R) return;

  double* Ed  = (double*)alloc((size_t)VOC*G4*8);
  int*    idx = (int*)   alloc((size_t)BS*4);
  double* h0  = (double*)alloc((size_t)R*HID*8);
  double* h1  = (double*)alloc((size_t)R*HID*8);
  double* cd  = (double*)alloc((size_t)R*HID*8);
  double* base = useBase ? (double*)alloc((size_t)R*G4*8) : nullptr;

  hipMemsetAsync(idx, 0, (size_t)BS*4, stream);
  ekernel_f64<<<dim3(16,17),256,0,stream>>>(emb, Wih, Ed);

  for (int c0 = 0; c0 < BS; c0 += R){
    if (useBase)
      base_f64<<<dim3(R/64, 64),256,0,stream>>>(wv + (size_t)c0*WVD, Wih, bih, bhh, base);
    hipMemsetAsync(cd, 0, (size_t)R*HID*8, stream);
    double* hb[2] = {h0, h1};
    for (int s = 0; s < NST; ++s){
      gates_v2<<<dim3(R/128, 32),256,0,stream>>>(
          hb[s&1], hb[(s+1)&1], cd, idx + c0, Ed, base,
          Whh, Wih, wv + (size_t)c0*WVD, bih, bhh,
          (s==0) ? 0 : HID/16, useBase ? 0 : 19);
      // logits partials written into the now-dead hb[s&1] buffer
      logits_sk<<<dim3(R/64, 5, 3),256,0,stream>>>(
          hb[(s+1)&1], Wlin, hb[s&1]);
      argmax_f64<<<R/4,256,0,stream>>>(
          hb[s&1], blin, idx + c0,
          out + (size_t)s*BS + c0, out + (size_t)NST*BS + (size_t)s*BS + c0);
    }
  }
}